// Round 2
// baseline (442.554 us; speedup 1.0000x reference)
//
#include <hip/hip_runtime.h>

typedef unsigned short u16;
typedef float  f32x4  __attribute__((ext_vector_type(4)));
typedef unsigned short u16x4 __attribute__((ext_vector_type(4)));
typedef short  bf16x8 __attribute__((ext_vector_type(8)));

__device__ __forceinline__ u16 f2bf(float f) {
  unsigned x = __builtin_bit_cast(unsigned, f);
  x += 0x7fffu + ((x >> 16) & 1u);           // RTN-even
  return (u16)(x >> 16);
}
__device__ __forceinline__ float bf2f(u16 u) {
  return __builtin_bit_cast(float, (unsigned)u << 16);
}

// ---------------- split fp32 -> (hi,lo) bf16 ----------------
__global__ void split_kernel(const float* __restrict__ x, u16* __restrict__ xh,
                             u16* __restrict__ xl, int n4) {
  int i = blockIdx.x * blockDim.x + threadIdx.x;
  int stride = gridDim.x * blockDim.x;
  for (; i < n4; i += stride) {
    f32x4 v = ((const f32x4*)x)[i];
    u16x4 h, l;
#pragma unroll
    for (int j = 0; j < 4; ++j) {
      u16 hh = f2bf(v[j]);
      h[j] = hh;
      l[j] = f2bf(v[j] - bf2f(hh));
    }
    ((u16x4*)xh)[i] = h;
    ((u16x4*)xl)[i] = l;
  }
}

// ---------------- transpose + split (for Wv) ----------------
__global__ void transpose_split_kernel(const float* __restrict__ W,
                                       u16* __restrict__ Th, u16* __restrict__ Tl) {
  int i = blockIdx.x * 256 + threadIdx.x;    // exactly 768*768 threads
  int h = i / 768, d = i % 768;
  float v = W[d * 768 + h];
  u16 hi = f2bf(v);
  Th[i] = hi;
  Tl[i] = f2bf(v - bf2f(hi));
}

// ---------------- GEMM: C = A * B^T ----------------
// A: (M,K) row-major (split hi/lo if SPLIT), B: (N,K) row-major (split),
// 128x128 tile, BK=32, 4 waves (2x2 of 64x64), 16x16x32 bf16 MFMA.
// EPI: 0 = f32 store (with causal mask if CAUSAL), 1 = split bf16 pair, 2 = bf16
// CAUSAL: skip tiles tj>ti, mask col>row to -1e30
// KROW: K_eff = (ti+1)*128 (PV causal K-limit)
#define GLL16(g, l)                                                              \
  __builtin_amdgcn_global_load_lds(                                              \
      (const __attribute__((address_space(1))) unsigned int*)(g),                \
      (__attribute__((address_space(3))) unsigned int*)(l), 16, 0, 0)

template <int SPLIT, int EPI, int CAUSAL, int KROW>
__global__ __launch_bounds__(256, 2) void gemm_k(
    const u16* __restrict__ Ah, const u16* __restrict__ Al, long sAb,
    const u16* __restrict__ Bh, const u16* __restrict__ Bl, long sBb,
    void* __restrict__ Cv, void* __restrict__ C2v, long sCb,
    int K, int lda, int ldb, int ldc) {
  const int tj = blockIdx.x, ti = blockIdx.y, zb = blockIdx.z;
  if (CAUSAL && tj > ti) return;
  Ah += (size_t)zb * sAb;
  Bh += (size_t)zb * sBb;
  if (SPLIT) { Al += (size_t)zb * sAb; Bl += (size_t)zb * sBb; }

  __shared__ __align__(16) u16 As[SPLIT ? 2 : 1][4096];  // [128][32] bf16
  __shared__ __align__(16) u16 Bs[SPLIT ? 2 : 1][4096];

  const int t = threadIdx.x, w = t >> 6, l = t & 63;
  const int wr = w >> 1, wc = w & 1;
  const int lr = l & 15, lk = l >> 4;

  // staging map: thread t covers LDS byte t*16 (chunk0) and t*16+4096 (chunk1)
  const int srow = t >> 2;
  const int sk8 = (t & 3) * 8;
  const size_t aOff0 = (size_t)(ti * 128 + srow) * lda + sk8;
  const size_t aOff1 = (size_t)(ti * 128 + 64 + srow) * lda + sk8;
  const size_t bOff0 = (size_t)(tj * 128 + srow) * ldb + sk8;
  const size_t bOff1 = (size_t)(tj * 128 + 64 + srow) * ldb + sk8;

  f32x4 acc[4][4] = {};
  const int Keff = KROW ? (ti + 1) * 128 : K;
  const int nsteps = Keff >> 5;

  for (int kk = 0; kk < nsteps; ++kk) {
    const int kbase = kk * 32;
    GLL16(Ah + aOff0 + kbase, &As[0][w * 512]);
    GLL16(Ah + aOff1 + kbase, &As[0][2048 + w * 512]);
    GLL16(Bh + bOff0 + kbase, &Bs[0][w * 512]);
    GLL16(Bh + bOff1 + kbase, &Bs[0][2048 + w * 512]);
    if (SPLIT) {
      GLL16(Al + aOff0 + kbase, &As[1][w * 512]);
      GLL16(Al + aOff1 + kbase, &As[1][2048 + w * 512]);
      GLL16(Bl + bOff0 + kbase, &Bs[1][w * 512]);
      GLL16(Bl + bOff1 + kbase, &Bs[1][2048 + w * 512]);
    }
    __syncthreads();  // compiler drains vmcnt before s_barrier

    bf16x8 ah[4], bh[4], al[4], bl[4];
#pragma unroll
    for (int mi = 0; mi < 4; ++mi) {
      const int ae = (wr * 64 + mi * 16 + lr) * 32 + lk * 8;
      const int be = (wc * 64 + mi * 16 + lr) * 32 + lk * 8;
      ah[mi] = *(const bf16x8*)&As[0][ae];
      bh[mi] = *(const bf16x8*)&Bs[0][be];
      if (SPLIT) {
        al[mi] = *(const bf16x8*)&As[1][ae];
        bl[mi] = *(const bf16x8*)&Bs[1][be];
      }
    }
#pragma unroll
    for (int mi = 0; mi < 4; ++mi)
#pragma unroll
      for (int ni = 0; ni < 4; ++ni) {
        acc[mi][ni] = __builtin_amdgcn_mfma_f32_16x16x32_bf16(ah[mi], bh[ni], acc[mi][ni], 0, 0, 0);
        if (SPLIT) {
          acc[mi][ni] = __builtin_amdgcn_mfma_f32_16x16x32_bf16(ah[mi], bl[ni], acc[mi][ni], 0, 0, 0);
          acc[mi][ni] = __builtin_amdgcn_mfma_f32_16x16x32_bf16(al[mi], bh[ni], acc[mi][ni], 0, 0, 0);
        }
      }
    __syncthreads();
  }

  // epilogue: C/D layout col = lane&15, row = (lane>>4)*4 + reg  [m89-verified]
#pragma unroll
  for (int mi = 0; mi < 4; ++mi)
#pragma unroll
    for (int ni = 0; ni < 4; ++ni)
#pragma unroll
      for (int r = 0; r < 4; ++r) {
        const int row = ti * 128 + wr * 64 + mi * 16 + lk * 4 + r;
        const int col = tj * 128 + wc * 64 + ni * 16 + lr;
        float v = acc[mi][ni][r];
        if (CAUSAL && col > row) v = -1e30f;
        const size_t idx = (size_t)zb * sCb + (size_t)row * ldc + col;
        if (EPI == 0) {
          ((float*)Cv)[idx] = v;
        } else if (EPI == 1) {
          u16 hv = f2bf(v);
          ((u16*)Cv)[idx] = hv;
          ((u16*)C2v)[idx] = f2bf(v - bf2f(hv));
        } else {
          ((u16*)Cv)[idx] = f2bf(v);
        }
      }
}

// ---------------- causal row softmax: scores f32 -> P bf16 ----------------
__global__ __launch_bounds__(256) void softmax_kernel(const float* __restrict__ S,
                                                      u16* __restrict__ P,
                                                      long sSb, long sPb) {
  const int wid = blockIdx.x * 4 + (threadIdx.x >> 6);  // one wave per row
  const int l = threadIdx.x & 63;
  const int zb = wid >> 11;
  const int i = wid & 2047;
  const float* row = S + (size_t)zb * sSb + (size_t)i * 2048;
  u16* prow = P + (size_t)zb * sPb + (size_t)i * 2048;
  const int Tend = ((i >> 7) + 1) << 7;  // multiple of 128
  const int nch = (Tend + 255) >> 8;

  f32x4 vb[8];
  float mx = -3e38f;
  for (int c = 0; c < nch; ++c) {
    const int j = c * 256 + l * 4;
    f32x4 v;
    if (j < Tend) v = *(const f32x4*)(row + j);
    else { v[0] = v[1] = v[2] = v[3] = -3e38f; }
    vb[c] = v;
    mx = fmaxf(mx, fmaxf(fmaxf(v[0], v[1]), fmaxf(v[2], v[3])));
  }
#pragma unroll
  for (int s = 32; s; s >>= 1) mx = fmaxf(mx, __shfl_xor(mx, s));

  float sum = 0.f;
  for (int c = 0; c < nch; ++c) {
    f32x4 v = vb[c];
#pragma unroll
    for (int j = 0; j < 4; ++j) {
      float e = expf(v[j] - mx);  // -1e30/-3e38 -> 0
      v[j] = e;
      sum += e;
    }
    vb[c] = v;
  }
#pragma unroll
  for (int s = 32; s; s >>= 1) sum += __shfl_xor(sum, s);
  const float inv = 1.f / sum;

  for (int c = 0; c < nch; ++c) {
    const int j = c * 256 + l * 4;
    if (j < Tend) {
      f32x4 v = vb[c];
      u16x4 o;
#pragma unroll
      for (int q = 0; q < 4; ++q) o[q] = f2bf(v[q] * inv);
      *(u16x4*)(prow + j) = o;
    }
  }
}

// ---------------- orchestration ----------------
extern "C" void kernel_launch(void* const* d_in, const int* in_sizes, int n_in,
                              void* d_out, int out_size, void* d_ws, size_t ws_size,
                              hipStream_t stream) {
  const float* x  = (const float*)d_in[0];
  const float* Wq = (const float*)d_in[1];
  const float* Wk = (const float*)d_in[2];
  const float* Wv = (const float*)d_in[3];
  float* out = (float*)d_out;

  const int S = 2048, D = 768;
  const size_t ND = (size_t)8 * S * D;        // 12.58M
  const size_t NW = (size_t)D * D;            // 589824

  char* ws = (char*)d_ws;
  size_t off = 0;
  auto alloc = [&](size_t bytes) { size_t o = off; off = (off + bytes + 255) & ~(size_t)255; return o; };

  u16* xh  = (u16*)(ws + alloc(ND * 2));
  u16* xl  = (u16*)(ws + alloc(ND * 2));
  u16* qh  = (u16*)(ws + alloc(ND * 2));
  u16* ql  = (u16*)(ws + alloc(ND * 2));
  u16* vt  = (u16*)(ws + alloc(ND * 2));
  u16* wqh = (u16*)(ws + alloc(NW * 2));
  u16* wql = (u16*)(ws + alloc(NW * 2));
  u16* wkh = (u16*)(ws + alloc(NW * 2));
  u16* wkl = (u16*)(ws + alloc(NW * 2));
  u16* wvth = (u16*)(ws + alloc(NW * 2));
  u16* wvtl = (u16*)(ws + alloc(NW * 2));
  u16* mth = (u16*)(ws + alloc(NW * 2));
  u16* mtl = (u16*)(ws + alloc(NW * 2));
  const size_t fixed = off;

  const size_t perBatch = (size_t)S * S * 4 + (size_t)S * S * 2 + 512;  // scores f32 + P bf16
  int g = 0;
  for (int cand = 8; cand >= 1; cand >>= 1)
    if (fixed + (size_t)cand * perBatch <= ws_size) { g = cand; break; }
  if (!g) return;  // insufficient workspace — will show as validation failure

  float* sc = (float*)(ws + alloc((size_t)g * S * S * 4));
  u16*   P  = (u16*)(ws + alloc((size_t)g * S * S * 2));

  // prep: splits
  split_kernel<<<2048, 256, 0, stream>>>(x, xh, xl, (int)(ND / 4));
  split_kernel<<<576, 256, 0, stream>>>(Wq, wqh, wql, (int)(NW / 4));
  split_kernel<<<576, 256, 0, stream>>>(Wk, wkh, wkl, (int)(NW / 4));
  transpose_split_kernel<<<2304, 256, 0, stream>>>(Wv, wvth, wvtl);

  // Mt[e][d] = sum_h Wk[e][h] * Wq[d][h]   (= (Wq Wk^T)^T), split output
  gemm_k<1, 1, 0, 0><<<dim3(6, 6, 1), 256, 0, stream>>>(
      wkh, wkl, 0, wqh, wql, 0, mth, mtl, 0, 768, 768, 768, 768);

  // q'[s][j] = sum_d x[s][d] * Mt[j][d], split output
  gemm_k<1, 1, 0, 0><<<dim3(6, 128, 1), 256, 0, stream>>>(
      xh, xl, 0, mth, mtl, 0, qh, ql, 0, 768, 768, 768, 768);

  // vt[h][b*2048+s] = sum_d WvT[h][d] * x[s][d]  (bf16 out)
  gemm_k<0, 2, 0, 0><<<dim3(128, 6, 1), 256, 0, stream>>>(
      wvth, nullptr, 0, xh, nullptr, 0, vt, nullptr, 0, 768, 768, 768, 16384);

  for (int b0 = 0; b0 < 8; b0 += g) {
    // scores[b][i][j] = q'[b,i] . x[b,j]  (causal tiles only, mask to -1e30)
    gemm_k<1, 0, 1, 0><<<dim3(16, 16, g), 256, 0, stream>>>(
        qh + (size_t)b0 * S * D, ql + (size_t)b0 * S * D, (long)S * D,
        xh + (size_t)b0 * S * D, xl + (size_t)b0 * S * D, (long)S * D,
        sc, nullptr, (long)S * S, 768, 768, 768, 2048);

    softmax_kernel<<<g * 512, 256, 0, stream>>>(sc, P, (long)S * S, (long)S * S);

    // out[b][i][h] = sum_{j<Tend} P[b][i][j] * vt[h][b*2048+j]
    gemm_k<0, 0, 0, 1><<<dim3(6, 16, g), 256, 0, stream>>>(
        P, nullptr, (long)S * S,
        vt + (size_t)b0 * S, nullptr, (long)S,
        out + (size_t)b0 * S * D, nullptr, (long)S * D,
        2048, 2048, 16384, 768);
  }
}

// Round 3
// 386.316 us; speedup vs baseline: 1.1456x; 1.1456x over previous
//
#include <hip/hip_runtime.h>

typedef unsigned short u16;
typedef float  f32x4  __attribute__((ext_vector_type(4)));
typedef unsigned short u16x4 __attribute__((ext_vector_type(4)));
typedef short  bf16x8 __attribute__((ext_vector_type(8)));

__device__ __forceinline__ u16 f2bf(float f) {
  unsigned x = __builtin_bit_cast(unsigned, f);
  x += 0x7fffu + ((x >> 16) & 1u);           // RTN-even
  return (u16)(x >> 16);
}
__device__ __forceinline__ float bf2f(u16 u) {
  return __builtin_bit_cast(float, (unsigned)u << 16);
}

// ---------------- split fp32 -> (hi,lo) bf16 ----------------
__global__ void split_kernel(const float* __restrict__ x, u16* __restrict__ xh,
                             u16* __restrict__ xl, int n4) {
  int i = blockIdx.x * blockDim.x + threadIdx.x;
  int stride = gridDim.x * blockDim.x;
  for (; i < n4; i += stride) {
    f32x4 v = ((const f32x4*)x)[i];
    u16x4 h, l;
#pragma unroll
    for (int j = 0; j < 4; ++j) {
      u16 hh = f2bf(v[j]);
      h[j] = hh;
      l[j] = f2bf(v[j] - bf2f(hh));
    }
    ((u16x4*)xh)[i] = h;
    ((u16x4*)xl)[i] = l;
  }
}

// ---------------- transpose + split (for Wv) ----------------
__global__ void transpose_split_kernel(const float* __restrict__ W,
                                       u16* __restrict__ Th, u16* __restrict__ Tl) {
  int i = blockIdx.x * 256 + threadIdx.x;    // exactly 768*768 threads
  int h = i / 768, d = i % 768;
  float v = W[d * 768 + h];
  u16 hi = f2bf(v);
  Th[i] = hi;
  Tl[i] = f2bf(v - bf2f(hi));
}

// ---------------- GEMM: C = A * B^T ----------------
// 128x128 tile, BK=32, 4 waves (2x2 of 64x64), 16x16x32 bf16 MFMA.
// Double-buffered LDS (stage t+1 before compute t, ONE barrier per K-step).
// Bank swizzle: LDS chunk c of row r holds global k-chunk c ^ ((r>>1)&3)
// (applied on the global source address; reader XORs the same bits).
// XCD-chunk bijective blockIdx remap (m204) for L2 locality.
// EPI: 0 = f32 store (+causal mask), 1 = split bf16 pair, 2 = bf16
#define GLL16(g, l)                                                              \
  __builtin_amdgcn_global_load_lds(                                              \
      (const __attribute__((address_space(1))) unsigned int*)(g),                \
      (__attribute__((address_space(3))) unsigned int*)(l), 16, 0, 0)

template <int SPLIT, int EPI, int CAUSAL, int KROW>
__global__ __launch_bounds__(256, 2) void gemm_k(
    const u16* __restrict__ Ah, const u16* __restrict__ Al, long sAb,
    const u16* __restrict__ Bh, const u16* __restrict__ Bl, long sBb,
    void* __restrict__ Cv, void* __restrict__ C2v, long sCb,
    int K, int lda, int ldb, int ldc, int gx, int gy) {
  // ---- bijective XCD-chunk remap ----
  const int nwg = gridDim.x;
  const int orig = blockIdx.x;
  const int q8 = nwg >> 3, r8 = nwg & 7;
  const int xcd = orig & 7, pos = orig >> 3;
  const int wgid = (xcd < r8 ? xcd * (q8 + 1) : r8 * (q8 + 1) + (xcd - r8) * q8) + pos;
  const int tj = wgid % gx;
  const int rest = wgid / gx;
  const int ti = rest % gy;
  const int zb = rest / gy;
  if (CAUSAL && tj > ti) return;

  const u16* pAh = Ah + (size_t)zb * sAb;
  const u16* pBh = Bh + (size_t)zb * sBb;
  const u16* pAl = SPLIT ? Al + (size_t)zb * sAb : nullptr;
  const u16* pBl = SPLIT ? Bl + (size_t)zb * sBb : nullptr;

  __shared__ __align__(16) u16 As[2][SPLIT ? 2 : 1][4096];  // [buf][hi/lo][128r x 32k]
  __shared__ __align__(16) u16 Bs[2][SPLIT ? 2 : 1][4096];

  const int t = threadIdx.x, w = t >> 6, l = t & 63;
  const int wr = w >> 1, wc = w & 1;
  const int lr = l & 15, lk = l >> 4;

  // staging: thread t -> LDS row t>>2, chunk t&3; global k-chunk is XOR-swizzled
  const int srow = t >> 2;
  const int sk8 = ((t & 3) ^ ((srow >> 1) & 3)) * 8;
  const size_t aOff0 = (size_t)(ti * 128 + srow) * lda + sk8;
  const size_t aOff1 = (size_t)(ti * 128 + 64 + srow) * lda + sk8;
  const size_t bOff0 = (size_t)(tj * 128 + srow) * ldb + sk8;
  const size_t bOff1 = (size_t)(tj * 128 + 64 + srow) * ldb + sk8;

  const int Keff = KROW ? (ti + 1) * 128 : K;
  const int nsteps = Keff >> 5;

  auto stage = [&](int bu, int kk) {
    const int kb = kk * 32;
    GLL16(pAh + aOff0 + kb, &As[bu][0][w * 512]);
    GLL16(pAh + aOff1 + kb, &As[bu][0][2048 + w * 512]);
    GLL16(pBh + bOff0 + kb, &Bs[bu][0][w * 512]);
    GLL16(pBh + bOff1 + kb, &Bs[bu][0][2048 + w * 512]);
    if constexpr (SPLIT) {
      GLL16(pAl + aOff0 + kb, &As[bu][1][w * 512]);
      GLL16(pAl + aOff1 + kb, &As[bu][1][2048 + w * 512]);
      GLL16(pBl + bOff0 + kb, &Bs[bu][1][w * 512]);
      GLL16(pBl + bOff1 + kb, &Bs[bu][1][2048 + w * 512]);
    }
  };

  f32x4 acc[4][4] = {};
  // swizzled chunk offset for fragment reads (row-bits come only from lr)
  const int ck = ((lk ^ ((lr >> 1) & 3)) << 3);

  stage(0, 0);
  __syncthreads();

  int buf = 0;
  for (int kk = 0; kk < nsteps; ++kk) {
    if (kk + 1 < nsteps) stage(buf ^ 1, kk + 1);  // loads fly during compute

    bf16x8 ah[4], bh[4], al[4], bl[4];
#pragma unroll
    for (int mi = 0; mi < 4; ++mi) {
      const int ae = (wr * 64 + mi * 16 + lr) * 32 + ck;
      const int be = (wc * 64 + mi * 16 + lr) * 32 + ck;
      ah[mi] = *(const bf16x8*)&As[buf][0][ae];
      bh[mi] = *(const bf16x8*)&Bs[buf][0][be];
      if constexpr (SPLIT) {
        al[mi] = *(const bf16x8*)&As[buf][1][ae];
        bl[mi] = *(const bf16x8*)&Bs[buf][1][be];
      }
    }
#pragma unroll
    for (int mi = 0; mi < 4; ++mi)
#pragma unroll
      for (int ni = 0; ni < 4; ++ni) {
        acc[mi][ni] = __builtin_amdgcn_mfma_f32_16x16x32_bf16(ah[mi], bh[ni], acc[mi][ni], 0, 0, 0);
        if constexpr (SPLIT) {
          acc[mi][ni] = __builtin_amdgcn_mfma_f32_16x16x32_bf16(ah[mi], bl[ni], acc[mi][ni], 0, 0, 0);
          acc[mi][ni] = __builtin_amdgcn_mfma_f32_16x16x32_bf16(al[mi], bh[ni], acc[mi][ni], 0, 0, 0);
        }
      }
    __syncthreads();  // drains vmcnt (next tile staged) + all reads of buf done
    buf ^= 1;
  }

  // epilogue: C/D layout col = lane&15, row = (lane>>4)*4 + reg  [m89-verified]
#pragma unroll
  for (int mi = 0; mi < 4; ++mi)
#pragma unroll
    for (int ni = 0; ni < 4; ++ni)
#pragma unroll
      for (int r = 0; r < 4; ++r) {
        const int row = ti * 128 + wr * 64 + mi * 16 + lk * 4 + r;
        const int col = tj * 128 + wc * 64 + ni * 16 + lr;
        float v = acc[mi][ni][r];
        if (CAUSAL && col > row) v = -1e30f;
        const size_t idx = (size_t)zb * sCb + (size_t)row * ldc + col;
        if (EPI == 0) {
          ((float*)Cv)[idx] = v;
        } else if (EPI == 1) {
          u16 hv = f2bf(v);
          ((u16*)Cv)[idx] = hv;
          ((u16*)C2v)[idx] = f2bf(v - bf2f(hv));
        } else {
          ((u16*)Cv)[idx] = f2bf(v);
        }
      }
}

// ---------------- causal row softmax: scores f32 -> P bf16 ----------------
__global__ __launch_bounds__(256) void softmax_kernel(const float* __restrict__ S,
                                                      u16* __restrict__ P,
                                                      long sSb, long sPb) {
  const int wid = blockIdx.x * 4 + (threadIdx.x >> 6);  // one wave per row
  const int l = threadIdx.x & 63;
  const int zb = wid >> 11;
  const int i = wid & 2047;
  const float* row = S + (size_t)zb * sSb + (size_t)i * 2048;
  u16* prow = P + (size_t)zb * sPb + (size_t)i * 2048;
  const int Tend = ((i >> 7) + 1) << 7;  // multiple of 128
  const int nch = (Tend + 255) >> 8;

  f32x4 vb[8];
  float mx = -3e38f;
  for (int c = 0; c < nch; ++c) {
    const int j = c * 256 + l * 4;
    f32x4 v;
    if (j < Tend) v = *(const f32x4*)(row + j);
    else { v[0] = v[1] = v[2] = v[3] = -3e38f; }
    vb[c] = v;
    mx = fmaxf(mx, fmaxf(fmaxf(v[0], v[1]), fmaxf(v[2], v[3])));
  }
#pragma unroll
  for (int s = 32; s; s >>= 1) mx = fmaxf(mx, __shfl_xor(mx, s));

  float sum = 0.f;
  for (int c = 0; c < nch; ++c) {
    f32x4 v = vb[c];
#pragma unroll
    for (int j = 0; j < 4; ++j) {
      float e = expf(v[j] - mx);  // -1e30/-3e38 -> 0
      v[j] = e;
      sum += e;
    }
    vb[c] = v;
  }
#pragma unroll
  for (int s = 32; s; s >>= 1) sum += __shfl_xor(sum, s);
  const float inv = 1.f / sum;

  for (int c = 0; c < nch; ++c) {
    const int j = c * 256 + l * 4;
    if (j < Tend) {
      f32x4 v = vb[c];
      u16x4 o;
#pragma unroll
      for (int q = 0; q < 4; ++q) o[q] = f2bf(v[q] * inv);
      *(u16x4*)(prow + j) = o;
    }
  }
}

// ---------------- orchestration ----------------
extern "C" void kernel_launch(void* const* d_in, const int* in_sizes, int n_in,
                              void* d_out, int out_size, void* d_ws, size_t ws_size,
                              hipStream_t stream) {
  const float* x  = (const float*)d_in[0];
  const float* Wq = (const float*)d_in[1];
  const float* Wk = (const float*)d_in[2];
  const float* Wv = (const float*)d_in[3];
  float* out = (float*)d_out;

  const int S = 2048, D = 768;
  const size_t ND = (size_t)8 * S * D;        // 12.58M
  const size_t NW = (size_t)D * D;            // 589824

  char* ws = (char*)d_ws;
  size_t off = 0;
  auto alloc = [&](size_t bytes) { size_t o = off; off = (off + bytes + 255) & ~(size_t)255; return o; };

  u16* xh  = (u16*)(ws + alloc(ND * 2));
  u16* xl  = (u16*)(ws + alloc(ND * 2));
  u16* qh  = (u16*)(ws + alloc(ND * 2));
  u16* ql  = (u16*)(ws + alloc(ND * 2));
  u16* vt  = (u16*)(ws + alloc(ND * 2));
  u16* wqh = (u16*)(ws + alloc(NW * 2));
  u16* wql = (u16*)(ws + alloc(NW * 2));
  u16* wkh = (u16*)(ws + alloc(NW * 2));
  u16* wkl = (u16*)(ws + alloc(NW * 2));
  u16* wvth = (u16*)(ws + alloc(NW * 2));
  u16* wvtl = (u16*)(ws + alloc(NW * 2));
  u16* mth = (u16*)(ws + alloc(NW * 2));
  u16* mtl = (u16*)(ws + alloc(NW * 2));
  const size_t fixed = off;

  const size_t perBatch = (size_t)S * S * 4 + (size_t)S * S * 2 + 512;  // scores f32 + P bf16
  int g = 0;
  for (int cand = 8; cand >= 1; cand >>= 1)
    if (fixed + (size_t)cand * perBatch <= ws_size) { g = cand; break; }
  if (!g) return;

  float* sc = (float*)(ws + alloc((size_t)g * S * S * 4));
  u16*   P  = (u16*)(ws + alloc((size_t)g * S * S * 2));

  // prep: splits
  split_kernel<<<2048, 256, 0, stream>>>(x, xh, xl, (int)(ND / 4));
  split_kernel<<<576, 256, 0, stream>>>(Wq, wqh, wql, (int)(NW / 4));
  split_kernel<<<576, 256, 0, stream>>>(Wk, wkh, wkl, (int)(NW / 4));
  transpose_split_kernel<<<2304, 256, 0, stream>>>(Wv, wvth, wvtl);

  // Mt[e][d] = sum_h Wk[e][h] * Wq[d][h]   (= (Wq Wk^T)^T), split output
  gemm_k<1, 1, 0, 0><<<36, 256, 0, stream>>>(
      wkh, wkl, 0, wqh, wql, 0, mth, mtl, 0, 768, 768, 768, 768, 6, 6);

  // q'[s][j] = sum_d x[s][d] * Mt[j][d], split output
  gemm_k<1, 1, 0, 0><<<768, 256, 0, stream>>>(
      xh, xl, 0, mth, mtl, 0, qh, ql, 0, 768, 768, 768, 768, 6, 128);

  // vt[h][b*2048+s] = sum_d WvT[h][d] * x[s][d]  (bf16 out)
  gemm_k<0, 2, 0, 0><<<768, 256, 0, stream>>>(
      wvth, nullptr, 0, xh, nullptr, 0, vt, nullptr, 0, 768, 768, 768, 16384, 128, 6);

  for (int b0 = 0; b0 < 8; b0 += g) {
    // scores[b][i][j] = q'[b,i] . x[b,j]  (causal tiles only, mask to -1e30)
    gemm_k<1, 0, 1, 0><<<16 * 16 * g, 256, 0, stream>>>(
        qh + (size_t)b0 * S * D, ql + (size_t)b0 * S * D, (long)S * D,
        xh + (size_t)b0 * S * D, xl + (size_t)b0 * S * D, (long)S * D,
        sc, nullptr, (long)S * S, 768, 768, 768, 2048, 16, 16);

    softmax_kernel<<<g * 512, 256, 0, stream>>>(sc, P, (long)S * S, (long)S * S);

    // out[b][i][h] = sum_{j<Tend} P[b][i][j] * vt[h][b*2048+j]
    gemm_k<0, 0, 0, 1><<<6 * 16 * g, 256, 0, stream>>>(
        P, nullptr, (long)S * S,
        vt + (size_t)b0 * S, nullptr, (long)S,
        out + (size_t)b0 * S * D, nullptr, (long)S * D,
        2048, 2048, 16384, 768, 6, 16);
  }
}